// Round 4
// baseline (682.400 us; speedup 1.0000x reference)
//
#include <hip/hip_runtime.h>

#define F_IN 500
#define F_HID 16
#define F_OUT 3
#define BN 256           // dst-nodes per bucket
#define CE 8192          // edges per chunk (multiple of 256)
#define MAXB 1024        // static LDS bucket-array bound (NBUCK=391)

__device__ __forceinline__ int clampi(int v, int lo, int hi) {
    return min(max(v, lo), hi);
}

// A: per-chunk bucket histogram (LDS) + fused per-node degree count
__global__ __launch_bounds__(256) void k_passA(const int* __restrict__ ei, int E, int N,
                                               int NBUCK, int* __restrict__ hist,
                                               int* __restrict__ degi) {
    __shared__ int lh[MAXB];
    int c = blockIdx.x;
    for (int i = threadIdx.x; i < NBUCK; i += 256) lh[i] = 0;
    __syncthreads();
    int base = c * CE, lim = min(base + CE, E);
    for (int e = base + threadIdx.x; e < lim; e += 256) {
        int d = clampi(ei[(size_t)E + e], 0, N - 1);
        atomicAdd(&lh[d >> 8], 1);
        atomicAdd(&degi[d], 1);
    }
    __syncthreads();
    for (int i = threadIdx.x; i < NBUCK; i += 256) hist[(size_t)c * NBUCK + i] = lh[i];
}

// S1: exclusive scan down each bucket column (over chunks); tot[b] = column total
__global__ __launch_bounds__(512) void k_scanchunks(int* __restrict__ hist, int NCH,
                                                    int NBUCK, int* __restrict__ tot) {
    __shared__ int s[512];
    int b = blockIdx.x, t = threadIdx.x;
    int v = (t < NCH) ? hist[(size_t)t * NBUCK + b] : 0;
    s[t] = v;
    __syncthreads();
    for (int off = 1; off < 512; off <<= 1) {
        int add = (t >= off) ? s[t - off] : 0;
        __syncthreads();
        s[t] += add;
        __syncthreads();
    }
    if (t < NCH) hist[(size_t)t * NBUCK + b] = s[t] - v;  // exclusive within column
    if (t == 511) tot[b] = s[511];
}

// S2: exclusive scan over bucket totals -> bstart[0..NBUCK], bstart[NBUCK]=E
__global__ __launch_bounds__(512) void k_scanbuckets(const int* __restrict__ tot, int NBUCK,
                                                     int E, int* __restrict__ bstart) {
    __shared__ int s[512];
    int t = threadIdx.x;
    int v = (t < NBUCK) ? tot[t] : 0;
    s[t] = v;
    __syncthreads();
    for (int off = 1; off < 512; off <<= 1) {
        int add = (t >= off) ? s[t - off] : 0;
        __syncthreads();
        s[t] += add;
        __syncthreads();
    }
    if (t < NBUCK) bstart[t] = s[t] - v;
    if (t == 0) bstart[NBUCK] = E;
}

// dinv = rsqrt(deg + 1)
__global__ void k_dinv(const int* __restrict__ degi, float* __restrict__ dinv, int N) {
    int i = blockIdx.x * blockDim.x + threadIdx.x;
    if (i >= N) return;
    dinv[i] = rsqrtf((float)degi[i] + 1.0f);
}

// B: scatter records (src<<8 | dst&255) into bucket-grouped ebuf2.
// Per-block active write footprint ~50 KB -> L2 line-combining, no 64B/4B amplification.
__global__ __launch_bounds__(256) void k_passB(const int* __restrict__ ei, int E, int N,
                                               int NBUCK, const int* __restrict__ hist,
                                               const int* __restrict__ bstart,
                                               unsigned* __restrict__ ebuf2) {
    __shared__ int loff[MAXB];
    __shared__ int lcnt[MAXB];
    int c = blockIdx.x;
    for (int i = threadIdx.x; i < NBUCK; i += 256) {
        loff[i] = bstart[i] + hist[(size_t)c * NBUCK + i];
        lcnt[i] = 0;
    }
    __syncthreads();
    int base = c * CE, lim = min(base + CE, E);
    for (int e = base + threadIdx.x; e < lim; e += 256) {
        int s = clampi(ei[e], 0, N - 1);
        int d = clampi(ei[(size_t)E + e], 0, N - 1);
        int b = d >> 8;
        int pos = loff[b] + atomicAdd(&lcnt[b], 1);
        ebuf2[pos] = ((unsigned)s << 8) | (unsigned)(d & 255);
    }
}

// hs1 = (x @ W1) * dinv[row]; wave = 4 rows x 16 cols, W1^T in LDS, 4 FMA chains
__global__ __launch_bounds__(256) void k_gemm1(const float* __restrict__ x,
                                               const float* __restrict__ W1,
                                               const float* __restrict__ dinv,
                                               float* __restrict__ hs1, int N) {
    __shared__ float w[F_HID * F_IN];  // w[j][k]
    for (int idx = threadIdx.x; idx < F_IN * F_HID; idx += 256) {
        int k = idx >> 4, j = idx & 15;
        w[j * F_IN + k] = W1[idx];
    }
    __syncthreads();
    int wave = threadIdx.x >> 6, lane = threadIdx.x & 63;
    int rsub = lane >> 4, j = lane & 15;
    int row = blockIdx.x * 16 + wave * 4 + rsub;
    if (row >= N) return;
    const float* xr = x + (size_t)row * F_IN;
    const float* wr = w + j * F_IN;
    float ax = 0.f, ay = 0.f, az = 0.f, aw = 0.f;
#pragma unroll 5
    for (int k = 0; k < F_IN; k += 4) {
        float4 xv = *(const float4*)(xr + k);
        float4 wv = *(const float4*)(wr + k);
        ax = fmaf(xv.x, wv.x, ax);
        ay = fmaf(xv.y, wv.y, ay);
        az = fmaf(xv.z, wv.z, az);
        aw = fmaf(xv.w, wv.w, aw);
    }
    hs1[(size_t)row * F_HID + j] = ((ax + ay) + (az + aw)) * dinv[row];
}

// agg layer1 (LDS accumulator per bucket) + fused gemm2: hs2 = (relu(agg)@W2)*dinv
__global__ __launch_bounds__(256) void k_agg1g2(const unsigned* __restrict__ ebuf2,
                                                const int* __restrict__ bstart,
                                                const float* __restrict__ hs1,
                                                const float* __restrict__ b1,
                                                const float* __restrict__ W2,
                                                const float* __restrict__ dinv,
                                                float* __restrict__ hs2, int N) {
    __shared__ float acc[BN][F_HID + 1];   // +1 pad: conflict-free epilogue
    __shared__ float w2[F_HID * F_OUT];
    __shared__ float b1s[F_HID];
    int b = blockIdx.x, t = threadIdx.x;
    for (int i = t; i < BN * (F_HID + 1); i += 256) ((float*)acc)[i] = 0.f;
    if (t < F_HID * F_OUT) w2[t] = W2[t];
    if (t < F_HID) b1s[t] = b1[t];
    __syncthreads();
    int s0 = bstart[b], s1 = bstart[b + 1];
    for (int i = s0 + t; i < s1; i += 256) {
        unsigned rec = ebuf2[i];
        int s = rec >> 8, dl = rec & 255;
        const float* hr = hs1 + (size_t)s * F_HID;
        float4 v0 = *(const float4*)(hr + 0);
        float4 v1 = *(const float4*)(hr + 4);
        float4 v2 = *(const float4*)(hr + 8);
        float4 v3 = *(const float4*)(hr + 12);
        float* a = acc[dl];
        atomicAdd(a + 0, v0.x);  atomicAdd(a + 1, v0.y);
        atomicAdd(a + 2, v0.z);  atomicAdd(a + 3, v0.w);
        atomicAdd(a + 4, v1.x);  atomicAdd(a + 5, v1.y);
        atomicAdd(a + 6, v1.z);  atomicAdd(a + 7, v1.w);
        atomicAdd(a + 8, v2.x);  atomicAdd(a + 9, v2.y);
        atomicAdd(a + 10, v2.z); atomicAdd(a + 11, v2.w);
        atomicAdd(a + 12, v3.x); atomicAdd(a + 13, v3.y);
        atomicAdd(a + 14, v3.z); atomicAdd(a + 15, v3.w);
    }
    __syncthreads();
    int node = b * BN + t;
    if (node < N) {
        float di = dinv[node];
        const float* hr = hs1 + (size_t)node * F_HID;
        float o0 = 0.f, o1 = 0.f, o2 = 0.f;
#pragma unroll
        for (int j = 0; j < F_HID; ++j) {
            float v = fmaxf(b1s[j] + di * (hr[j] + acc[t][j]), 0.f);
            o0 = fmaf(v, w2[j * 3 + 0], o0);
            o1 = fmaf(v, w2[j * 3 + 1], o1);
            o2 = fmaf(v, w2[j * 3 + 2], o2);
        }
        hs2[(size_t)node * 3 + 0] = o0 * di;
        hs2[(size_t)node * 3 + 1] = o1 * di;
        hs2[(size_t)node * 3 + 2] = o2 * di;
    }
}

// agg layer2 + fused log_softmax -> out
__global__ __launch_bounds__(256) void k_agg2lsm(const unsigned* __restrict__ ebuf2,
                                                 const int* __restrict__ bstart,
                                                 const float* __restrict__ hs2,
                                                 const float* __restrict__ b2,
                                                 const float* __restrict__ dinv,
                                                 float* __restrict__ out, int N) {
    __shared__ float acc[BN][5];   // stride 5: bank spread
    int b = blockIdx.x, t = threadIdx.x;
    for (int i = t; i < BN * 5; i += 256) ((float*)acc)[i] = 0.f;
    __syncthreads();
    int s0 = bstart[b], s1 = bstart[b + 1];
    for (int i = s0 + t; i < s1; i += 256) {
        unsigned rec = ebuf2[i];
        int s = rec >> 8, dl = rec & 255;
        const float* hr = hs2 + (size_t)s * 3;
        float* a = acc[dl];
        atomicAdd(a + 0, hr[0]);
        atomicAdd(a + 1, hr[1]);
        atomicAdd(a + 2, hr[2]);
    }
    __syncthreads();
    int node = b * BN + t;
    if (node < N) {
        float di = dinv[node];
        const float* hr = hs2 + (size_t)node * 3;
        float a0 = b2[0] + di * (hr[0] + acc[t][0]);
        float a1 = b2[1] + di * (hr[1] + acc[t][1]);
        float a2 = b2[2] + di * (hr[2] + acc[t][2]);
        float m = fmaxf(a0, fmaxf(a1, a2));
        float l = logf(expf(a0 - m) + expf(a1 - m) + expf(a2 - m));
        out[(size_t)node * 3 + 0] = a0 - m - l;
        out[(size_t)node * 3 + 1] = a1 - m - l;
        out[(size_t)node * 3 + 2] = a2 - m - l;
    }
}

extern "C" void kernel_launch(void* const* d_in, const int* in_sizes, int n_in,
                              void* d_out, int out_size, void* d_ws, size_t ws_size,
                              hipStream_t stream) {
    const float* x = (const float*)d_in[0];
    const int* ei = (const int*)d_in[1];
    const float* W1 = (const float*)d_in[2];
    const float* b1 = (const float*)d_in[3];
    const float* W2 = (const float*)d_in[4];
    const float* b2 = (const float*)d_in[5];
    float* out = (float*)d_out;

    const int N = in_sizes[0] / F_IN;        // 100000
    const int E = in_sizes[1] / 2;           // 3200000
    const int NBUCK = (N + BN - 1) / BN;     // 391  (<=512 required)
    const int NCH = (E + CE - 1) / CE;       // 391  (<=512 required)

    char* p = (char*)d_ws;
    auto alloc = [&](size_t bytes) {
        char* r = p;
        p += (bytes + 255) & ~(size_t)255;
        return r;
    };
    int*      degi   = (int*)alloc((size_t)N * 4);
    float*    dinv   = (float*)alloc((size_t)N * 4);
    int*      hist   = (int*)alloc((size_t)NCH * NBUCK * 4);   // ~612 KB
    int*      tot    = (int*)alloc((size_t)NBUCK * 4);
    int*      bstart = (int*)alloc(((size_t)NBUCK + 1) * 4);
    unsigned* ebuf2  = (unsigned*)alloc((size_t)E * 4);        // 12.8 MB
    float*    hs1    = (float*)alloc((size_t)N * F_HID * 4);   // 6.4 MB
    float*    hs2    = (float*)alloc((size_t)N * F_OUT * 4);   // 1.2 MB

    hipMemsetAsync(degi, 0, (size_t)N * 4, stream);

    k_passA<<<NCH, 256, 0, stream>>>(ei, E, N, NBUCK, hist, degi);
    k_dinv<<<(N + 255) / 256, 256, 0, stream>>>(degi, dinv, N);
    k_scanchunks<<<NBUCK, 512, 0, stream>>>(hist, NCH, NBUCK, tot);
    k_scanbuckets<<<1, 512, 0, stream>>>(tot, NBUCK, E, bstart);
    k_passB<<<NCH, 256, 0, stream>>>(ei, E, N, NBUCK, hist, bstart, ebuf2);
    k_gemm1<<<(N + 15) / 16, 256, 0, stream>>>(x, W1, dinv, hs1, N);
    k_agg1g2<<<NBUCK, 256, 0, stream>>>(ebuf2, bstart, hs1, b1, W2, dinv, hs2, N);
    k_agg2lsm<<<NBUCK, 256, 0, stream>>>(ebuf2, bstart, hs2, b2, dinv, out, N);
}

// Round 5
// 666.660 us; speedup vs baseline: 1.0236x; 1.0236x over previous
//
#include <hip/hip_runtime.h>

#define F_IN 500
#define F_HID 16
#define F_OUT 3
#define BN 64            // dst-nodes per bucket
#define CE 8192          // edges per chunk
#define MAXB 2048        // static LDS bound, >= NBUCK=1563
#define WPAD 501         // padded W1 row stride in LDS (gcd(501%32,32)=1 -> conflict-free)

__device__ __forceinline__ int clampi(int v, int lo, int hi) {
    return min(max(v, lo), hi);
}

// A: per-chunk bucket histogram (LDS) + fused per-node degree count
__global__ __launch_bounds__(1024) void k_passA(const int* __restrict__ ei, int E, int N,
                                                int NBUCK, int* __restrict__ hist,
                                                int* __restrict__ degi) {
    __shared__ int lh[MAXB];
    int c = blockIdx.x;
    for (int i = threadIdx.x; i < NBUCK; i += 1024) lh[i] = 0;
    __syncthreads();
    int base = c * CE, lim = min(base + CE, E);
    for (int e = base + (int)threadIdx.x; e < lim; e += 1024) {
        int d = clampi(ei[(size_t)E + e], 0, N - 1);
        atomicAdd(&lh[d >> 6], 1);
        atomicAdd(&degi[d], 1);
    }
    __syncthreads();
    for (int i = threadIdx.x; i < NBUCK; i += 1024) hist[(size_t)c * NBUCK + i] = lh[i];
}

// S1: exclusive scan down each bucket column (over NCH<=512 chunks); tot[b]=column total
__global__ __launch_bounds__(512) void k_scanchunks(int* __restrict__ hist, int NCH,
                                                    int NBUCK, int* __restrict__ tot) {
    __shared__ int s[512];
    int b = blockIdx.x, t = threadIdx.x;
    int v = (t < NCH) ? hist[(size_t)t * NBUCK + b] : 0;
    s[t] = v;
    __syncthreads();
    for (int off = 1; off < 512; off <<= 1) {
        int add = (t >= off) ? s[t - off] : 0;
        __syncthreads();
        s[t] += add;
        __syncthreads();
    }
    if (t < NCH) hist[(size_t)t * NBUCK + b] = s[t] - v;  // exclusive within column
    if (t == 511) tot[b] = s[511];
}

// S2: exclusive scan over NBUCK bucket totals (NBUCK may exceed 512: 4 elems/thread)
__global__ __launch_bounds__(512) void k_scanbuckets(const int* __restrict__ tot, int NBUCK,
                                                     int E, int* __restrict__ bstart) {
    __shared__ int s[512];
    int t = threadIdx.x;
    int per = (NBUCK + 511) / 512;
    int lo = t * per, hi = min(lo + per, NBUCK);
    int sum = 0;
    for (int i = lo; i < hi; ++i) sum += tot[i];
    s[t] = sum;
    __syncthreads();
    for (int off = 1; off < 512; off <<= 1) {
        int add = (t >= off) ? s[t - off] : 0;
        __syncthreads();
        s[t] += add;
        __syncthreads();
    }
    int run = s[t] - sum;  // exclusive prefix of this thread's range
    for (int i = lo; i < hi; ++i) {
        bstart[i] = run;
        run += tot[i];
    }
    if (t == 0) bstart[NBUCK] = E;
}

// dinv = rsqrt(deg + 1)
__global__ void k_dinv(const int* __restrict__ degi, float* __restrict__ dinv, int N) {
    int i = blockIdx.x * blockDim.x + threadIdx.x;
    if (i >= N) return;
    dinv[i] = rsqrtf((float)degi[i] + 1.0f);
}

// B: scatter records (src<<6 | dst&63) into bucket-grouped ebuf2 (line-friendly writes)
__global__ __launch_bounds__(1024) void k_passB(const int* __restrict__ ei, int E, int N,
                                                int NBUCK, const int* __restrict__ hist,
                                                const int* __restrict__ bstart,
                                                unsigned* __restrict__ ebuf2) {
    __shared__ int loff[MAXB];
    __shared__ int lcnt[MAXB];
    int c = blockIdx.x;
    for (int i = threadIdx.x; i < NBUCK; i += 1024) {
        loff[i] = bstart[i] + hist[(size_t)c * NBUCK + i];
        lcnt[i] = 0;
    }
    __syncthreads();
    int base = c * CE, lim = min(base + CE, E);
    for (int e = base + (int)threadIdx.x; e < lim; e += 1024) {
        int s = clampi(ei[e], 0, N - 1);
        int d = clampi(ei[(size_t)E + e], 0, N - 1);
        int b = d >> 6;
        int pos = loff[b] + atomicAdd(&lcnt[b], 1);
        ebuf2[pos] = ((unsigned)s << 6) | (unsigned)(d & 63);
    }
}

// hs1 = (x @ W1) * dinv[row]; thread = 4 rows x 1 col; wave = 16 cols x 4 row-slots
__global__ __launch_bounds__(256) void k_gemm1(const float* __restrict__ x,
                                               const float* __restrict__ W1,
                                               const float* __restrict__ dinv,
                                               float* __restrict__ hs1, int N) {
    __shared__ float w[F_HID * WPAD];  // w[j][k], padded stride 501
    for (int idx = threadIdx.x; idx < F_IN * F_HID; idx += 256) {
        int k = idx >> 4, j = idx & 15;
        w[j * WPAD + k] = W1[idx];
    }
    __syncthreads();
    int wave = threadIdx.x >> 6, lane = threadIdx.x & 63;
    int slot = lane >> 4, j = lane & 15;
    int r0 = blockIdx.x * 64 + wave * 16 + slot * 4;
    const float* wr = w + j * WPAD;
    if (r0 + 4 <= N) {
        const float* x0 = x + (size_t)r0 * F_IN;
        float a0 = 0.f, a1 = 0.f, a2 = 0.f, a3 = 0.f;
#pragma unroll 5
        for (int k = 0; k < F_IN; k += 4) {
            float4 wv = *(const float4*)(wr + k);
            float4 v0 = *(const float4*)(x0 + k);
            float4 v1 = *(const float4*)(x0 + F_IN + k);
            float4 v2 = *(const float4*)(x0 + 2 * F_IN + k);
            float4 v3 = *(const float4*)(x0 + 3 * F_IN + k);
            a0 = fmaf(v0.x, wv.x, fmaf(v0.y, wv.y, fmaf(v0.z, wv.z, fmaf(v0.w, wv.w, a0))));
            a1 = fmaf(v1.x, wv.x, fmaf(v1.y, wv.y, fmaf(v1.z, wv.z, fmaf(v1.w, wv.w, a1))));
            a2 = fmaf(v2.x, wv.x, fmaf(v2.y, wv.y, fmaf(v2.z, wv.z, fmaf(v2.w, wv.w, a2))));
            a3 = fmaf(v3.x, wv.x, fmaf(v3.y, wv.y, fmaf(v3.z, wv.z, fmaf(v3.w, wv.w, a3))));
        }
        hs1[(size_t)(r0 + 0) * F_HID + j] = a0 * dinv[r0 + 0];
        hs1[(size_t)(r0 + 1) * F_HID + j] = a1 * dinv[r0 + 1];
        hs1[(size_t)(r0 + 2) * F_HID + j] = a2 * dinv[r0 + 2];
        hs1[(size_t)(r0 + 3) * F_HID + j] = a3 * dinv[r0 + 3];
    } else {
        for (int rr = 0; rr < 4; ++rr) {
            int r = r0 + rr;
            if (r >= N) break;
            float b0 = 0.f, b1v = 0.f, b2v = 0.f, b3 = 0.f;
            const float* xr = x + (size_t)r * F_IN;
            for (int k = 0; k < F_IN; k += 4) {
                float4 xv = *(const float4*)(xr + k);
                float4 wv = *(const float4*)(wr + k);
                b0 = fmaf(xv.x, wv.x, b0);
                b1v = fmaf(xv.y, wv.y, b1v);
                b2v = fmaf(xv.z, wv.z, b2v);
                b3 = fmaf(xv.w, wv.w, b3);
            }
            hs1[(size_t)r * F_HID + j] = ((b0 + b1v) + (b2v + b3)) * dinv[r];
        }
    }
}

// agg layer1 (LDS acc per 64-node bucket, 2-deep gather pipeline) + fused gemm2
__global__ __launch_bounds__(512) void k_agg1g2(const unsigned* __restrict__ ebuf2,
                                                const int* __restrict__ bstart,
                                                const float* __restrict__ hs1,
                                                const float* __restrict__ b1,
                                                const float* __restrict__ W2,
                                                const float* __restrict__ dinv,
                                                float* __restrict__ hs2, int N) {
    __shared__ float acc[BN][F_HID + 1];   // pad 17: epilogue + atomic bank spread
    __shared__ float w2[F_HID * F_OUT];
    __shared__ float b1s[F_HID];
    int b = blockIdx.x, t = threadIdx.x;
    for (int i = t; i < BN * (F_HID + 1); i += 512) ((float*)acc)[i] = 0.f;
    if (t < F_HID * F_OUT) w2[t] = W2[t];
    if (t < F_HID) b1s[t] = b1[t];
    __syncthreads();
    int s0 = bstart[b], s1 = bstart[b + 1];
    int i = s0 + t;
#define GATHER16(rec)                                                     \
    {                                                                     \
        const float* hr = hs1 + (size_t)((rec) >> 6) * F_HID;             \
        float4 v0 = *(const float4*)(hr + 0);                             \
        float4 v1 = *(const float4*)(hr + 4);                             \
        float4 v2 = *(const float4*)(hr + 8);                             \
        float4 v3 = *(const float4*)(hr + 12);                            \
        float* a = acc[(rec) & 63];                                       \
        atomicAdd(a + 0, v0.x);  atomicAdd(a + 1, v0.y);                  \
        atomicAdd(a + 2, v0.z);  atomicAdd(a + 3, v0.w);                  \
        atomicAdd(a + 4, v1.x);  atomicAdd(a + 5, v1.y);                  \
        atomicAdd(a + 6, v1.z);  atomicAdd(a + 7, v1.w);                  \
        atomicAdd(a + 8, v2.x);  atomicAdd(a + 9, v2.y);                  \
        atomicAdd(a + 10, v2.z); atomicAdd(a + 11, v2.w);                 \
        atomicAdd(a + 12, v3.x); atomicAdd(a + 13, v3.y);                 \
        atomicAdd(a + 14, v3.z); atomicAdd(a + 15, v3.w);                 \
    }
    for (; i + 512 < s1; i += 1024) {
        unsigned rA = ebuf2[i];
        unsigned rB = ebuf2[i + 512];
        GATHER16(rA);
        GATHER16(rB);
    }
    if (i < s1) {
        unsigned rA = ebuf2[i];
        GATHER16(rA);
    }
#undef GATHER16
    __syncthreads();
    if (t < BN) {
        int node = b * BN + t;
        if (node < N) {
            float di = dinv[node];
            const float* hr = hs1 + (size_t)node * F_HID;
            float o0 = 0.f, o1 = 0.f, o2 = 0.f;
#pragma unroll
            for (int j = 0; j < F_HID; ++j) {
                float v = fmaxf(b1s[j] + di * (hr[j] + acc[t][j]), 0.f);
                o0 = fmaf(v, w2[j * 3 + 0], o0);
                o1 = fmaf(v, w2[j * 3 + 1], o1);
                o2 = fmaf(v, w2[j * 3 + 2], o2);
            }
            hs2[(size_t)node * 3 + 0] = o0 * di;
            hs2[(size_t)node * 3 + 1] = o1 * di;
            hs2[(size_t)node * 3 + 2] = o2 * di;
        }
    }
}

// agg layer2 + fused log_softmax -> out
__global__ __launch_bounds__(256) void k_agg2lsm(const unsigned* __restrict__ ebuf2,
                                                 const int* __restrict__ bstart,
                                                 const float* __restrict__ hs2,
                                                 const float* __restrict__ b2,
                                                 const float* __restrict__ dinv,
                                                 float* __restrict__ out, int N) {
    __shared__ float acc[BN][4];
    int b = blockIdx.x, t = threadIdx.x;
    for (int i = t; i < BN * 4; i += 256) ((float*)acc)[i] = 0.f;
    __syncthreads();
    int s0 = bstart[b], s1 = bstart[b + 1];
    int i = s0 + t;
#define GATHER3(rec)                                          \
    {                                                         \
        const float* hr = hs2 + (size_t)((rec) >> 6) * 3;     \
        float v0 = hr[0], v1 = hr[1], v2 = hr[2];             \
        float* a = acc[(rec) & 63];                           \
        atomicAdd(a + 0, v0);                                 \
        atomicAdd(a + 1, v1);                                 \
        atomicAdd(a + 2, v2);                                 \
    }
    for (; i + 256 < s1; i += 512) {
        unsigned rA = ebuf2[i];
        unsigned rB = ebuf2[i + 256];
        GATHER3(rA);
        GATHER3(rB);
    }
    if (i < s1) {
        unsigned rA = ebuf2[i];
        GATHER3(rA);
    }
#undef GATHER3
    __syncthreads();
    if (t < BN) {
        int node = b * BN + t;
        if (node < N) {
            float di = dinv[node];
            const float* hr = hs2 + (size_t)node * 3;
            float a0 = b2[0] + di * (hr[0] + acc[t][0]);
            float a1 = b2[1] + di * (hr[1] + acc[t][1]);
            float a2 = b2[2] + di * (hr[2] + acc[t][2]);
            float m = fmaxf(a0, fmaxf(a1, a2));
            float l = logf(expf(a0 - m) + expf(a1 - m) + expf(a2 - m));
            out[(size_t)node * 3 + 0] = a0 - m - l;
            out[(size_t)node * 3 + 1] = a1 - m - l;
            out[(size_t)node * 3 + 2] = a2 - m - l;
        }
    }
}

extern "C" void kernel_launch(void* const* d_in, const int* in_sizes, int n_in,
                              void* d_out, int out_size, void* d_ws, size_t ws_size,
                              hipStream_t stream) {
    const float* x = (const float*)d_in[0];
    const int* ei = (const int*)d_in[1];
    const float* W1 = (const float*)d_in[2];
    const float* b1 = (const float*)d_in[3];
    const float* W2 = (const float*)d_in[4];
    const float* b2 = (const float*)d_in[5];
    float* out = (float*)d_out;

    const int N = in_sizes[0] / F_IN;        // 100000
    const int E = in_sizes[1] / 2;           // 3200000
    const int NBUCK = (N + BN - 1) / BN;     // 1563 (<=MAXB)
    const int NCH = (E + CE - 1) / CE;       // 391  (<=512 required by k_scanchunks)

    char* p = (char*)d_ws;
    auto alloc = [&](size_t bytes) {
        char* r = p;
        p += (bytes + 255) & ~(size_t)255;
        return r;
    };
    int*      degi   = (int*)alloc((size_t)N * 4);
    float*    dinv   = (float*)alloc((size_t)N * 4);
    int*      hist   = (int*)alloc((size_t)NCH * NBUCK * 4);   // ~2.4 MB
    int*      tot    = (int*)alloc((size_t)NBUCK * 4);
    int*      bstart = (int*)alloc(((size_t)NBUCK + 1) * 4);
    unsigned* ebuf2  = (unsigned*)alloc((size_t)E * 4);        // 12.8 MB
    float*    hs1    = (float*)alloc((size_t)N * F_HID * 4);   // 6.4 MB
    float*    hs2    = (float*)alloc((size_t)N * F_OUT * 4);   // 1.2 MB

    hipMemsetAsync(degi, 0, (size_t)N * 4, stream);

    k_passA<<<NCH, 1024, 0, stream>>>(ei, E, N, NBUCK, hist, degi);
    k_dinv<<<(N + 255) / 256, 256, 0, stream>>>(degi, dinv, N);
    k_scanchunks<<<NBUCK, 512, 0, stream>>>(hist, NCH, NBUCK, tot);
    k_scanbuckets<<<1, 512, 0, stream>>>(tot, NBUCK, E, bstart);
    k_passB<<<NCH, 1024, 0, stream>>>(ei, E, N, NBUCK, hist, bstart, ebuf2);
    k_gemm1<<<(N + 63) / 64, 256, 0, stream>>>(x, W1, dinv, hs1, N);
    k_agg1g2<<<NBUCK, 512, 0, stream>>>(ebuf2, bstart, hs1, b1, W2, dinv, hs2, N);
    k_agg2lsm<<<NBUCK, 256, 0, stream>>>(ebuf2, bstart, hs2, b2, dinv, out, N);
}

// Round 6
// 662.562 us; speedup vs baseline: 1.0299x; 1.0062x over previous
//
#include <hip/hip_runtime.h>
#include <hip/hip_bf16.h>

#define F_IN 500
#define F_HID 16
#define F_OUT 3
#define BN 64            // dst-nodes per bucket
#define CE 8192          // edges per chunk
#define MAXB 2048        // static LDS bound, >= NBUCK=1563
#define WPAD 501         // padded W1 row stride in LDS
#define SENT 0xFFFFFFFFu

__device__ __forceinline__ int clampi(int v, int lo, int hi) {
    return min(max(v, lo), hi);
}

// A: per-chunk bucket histogram (LDS) + fused per-node degree count
__global__ __launch_bounds__(1024) void k_passA(const int* __restrict__ ei, int E, int N,
                                                int NBUCK, int* __restrict__ hist,
                                                int* __restrict__ degi) {
    __shared__ int lh[MAXB];
    int c = blockIdx.x;
    for (int i = threadIdx.x; i < NBUCK; i += 1024) lh[i] = 0;
    __syncthreads();
    int base = c * CE, lim = min(base + CE, E);
    for (int e = base + (int)threadIdx.x; e < lim; e += 1024) {
        int d = clampi(ei[(size_t)E + e], 0, N - 1);
        atomicAdd(&lh[d >> 6], 1);
        atomicAdd(&degi[d], 1);
    }
    __syncthreads();
    for (int i = threadIdx.x; i < NBUCK; i += 1024) hist[(size_t)c * NBUCK + i] = lh[i];
}

// S1: exclusive scan down each bucket column (over NCH<=512 chunks); tot[b]=column total
__global__ __launch_bounds__(512) void k_scanchunks(int* __restrict__ hist, int NCH,
                                                    int NBUCK, int* __restrict__ tot) {
    __shared__ int s[512];
    int b = blockIdx.x, t = threadIdx.x;
    int v = (t < NCH) ? hist[(size_t)t * NBUCK + b] : 0;
    s[t] = v;
    __syncthreads();
    for (int off = 1; off < 512; off <<= 1) {
        int add = (t >= off) ? s[t - off] : 0;
        __syncthreads();
        s[t] += add;
        __syncthreads();
    }
    if (t < NCH) hist[(size_t)t * NBUCK + b] = s[t] - v;  // exclusive within column
    if (t == 511) tot[b] = s[511];
}

// S2: exclusive scan over NBUCK bucket totals (NBUCK>512: strided per-thread ranges)
__global__ __launch_bounds__(512) void k_scanbuckets(const int* __restrict__ tot, int NBUCK,
                                                     int E, int* __restrict__ bstart) {
    __shared__ int s[512];
    int t = threadIdx.x;
    int per = (NBUCK + 511) / 512;
    int lo = t * per, hi = min(lo + per, NBUCK);
    int sum = 0;
    for (int i = lo; i < hi; ++i) sum += tot[i];
    s[t] = sum;
    __syncthreads();
    for (int off = 1; off < 512; off <<= 1) {
        int add = (t >= off) ? s[t - off] : 0;
        __syncthreads();
        s[t] += add;
        __syncthreads();
    }
    int run = s[t] - sum;
    for (int i = lo; i < hi; ++i) {
        bstart[i] = run;
        run += tot[i];
    }
    if (t == 0) bstart[NBUCK] = E;
}

// dinv = rsqrt(deg + 1)
__global__ void k_dinv(const int* __restrict__ degi, float* __restrict__ dinv, int N) {
    int i = blockIdx.x * blockDim.x + threadIdx.x;
    if (i >= N) return;
    dinv[i] = rsqrtf((float)degi[i] + 1.0f);
}

// B: scatter records (src<<6 | dst&63) into bucket-grouped ebuf2
__global__ __launch_bounds__(1024) void k_passB(const int* __restrict__ ei, int E, int N,
                                                int NBUCK, const int* __restrict__ hist,
                                                const int* __restrict__ bstart,
                                                unsigned* __restrict__ ebuf2) {
    __shared__ int loff[MAXB];
    __shared__ int lcnt[MAXB];
    int c = blockIdx.x;
    for (int i = threadIdx.x; i < NBUCK; i += 1024) {
        loff[i] = bstart[i] + hist[(size_t)c * NBUCK + i];
        lcnt[i] = 0;
    }
    __syncthreads();
    int base = c * CE, lim = min(base + CE, E);
    for (int e = base + (int)threadIdx.x; e < lim; e += 1024) {
        int s = clampi(ei[e], 0, N - 1);
        int d = clampi(ei[(size_t)E + e], 0, N - 1);
        int b = d >> 6;
        int pos = loff[b] + atomicAdd(&lcnt[b], 1);
        ebuf2[pos] = ((unsigned)s << 6) | (unsigned)(d & 63);
    }
}

// hs1b = bf16( (x @ W1) * dinv[row] ); thread = 4 rows x 1 col
__global__ __launch_bounds__(256) void k_gemm1(const float* __restrict__ x,
                                               const float* __restrict__ W1,
                                               const float* __restrict__ dinv,
                                               __hip_bfloat16* __restrict__ hs1b, int N) {
    __shared__ float w[F_HID * WPAD];  // w[j][k], padded stride
    for (int idx = threadIdx.x; idx < F_IN * F_HID; idx += 256) {
        int k = idx >> 4, j = idx & 15;
        w[j * WPAD + k] = W1[idx];
    }
    __syncthreads();
    int wave = threadIdx.x >> 6, lane = threadIdx.x & 63;
    int slot = lane >> 4, j = lane & 15;
    int r0 = blockIdx.x * 64 + wave * 16 + slot * 4;
    const float* wr = w + j * WPAD;
    if (r0 + 4 <= N) {
        const float* x0 = x + (size_t)r0 * F_IN;
        float a0 = 0.f, a1 = 0.f, a2 = 0.f, a3 = 0.f;
#pragma unroll 5
        for (int k = 0; k < F_IN; k += 4) {
            float4 wv = *(const float4*)(wr + k);
            float4 v0 = *(const float4*)(x0 + k);
            float4 v1 = *(const float4*)(x0 + F_IN + k);
            float4 v2 = *(const float4*)(x0 + 2 * F_IN + k);
            float4 v3 = *(const float4*)(x0 + 3 * F_IN + k);
            a0 = fmaf(v0.x, wv.x, fmaf(v0.y, wv.y, fmaf(v0.z, wv.z, fmaf(v0.w, wv.w, a0))));
            a1 = fmaf(v1.x, wv.x, fmaf(v1.y, wv.y, fmaf(v1.z, wv.z, fmaf(v1.w, wv.w, a1))));
            a2 = fmaf(v2.x, wv.x, fmaf(v2.y, wv.y, fmaf(v2.z, wv.z, fmaf(v2.w, wv.w, a2))));
            a3 = fmaf(v3.x, wv.x, fmaf(v3.y, wv.y, fmaf(v3.z, wv.z, fmaf(v3.w, wv.w, a3))));
        }
        hs1b[(size_t)(r0 + 0) * F_HID + j] = __float2bfloat16(a0 * dinv[r0 + 0]);
        hs1b[(size_t)(r0 + 1) * F_HID + j] = __float2bfloat16(a1 * dinv[r0 + 1]);
        hs1b[(size_t)(r0 + 2) * F_HID + j] = __float2bfloat16(a2 * dinv[r0 + 2]);
        hs1b[(size_t)(r0 + 3) * F_HID + j] = __float2bfloat16(a3 * dinv[r0 + 3]);
    } else {
        for (int rr = 0; rr < 4; ++rr) {
            int r = r0 + rr;
            if (r >= N) break;
            float b0 = 0.f, b1v = 0.f, b2v = 0.f, b3 = 0.f;
            const float* xr = x + (size_t)r * F_IN;
            for (int k = 0; k < F_IN; k += 4) {
                float4 xv = *(const float4*)(xr + k);
                float4 wv = *(const float4*)(wr + k);
                b0 = fmaf(xv.x, wv.x, b0);
                b1v = fmaf(xv.y, wv.y, b1v);
                b2v = fmaf(xv.z, wv.z, b2v);
                b3 = fmaf(xv.w, wv.w, b3);
            }
            hs1b[(size_t)r * F_HID + j] = __float2bfloat16(((b0 + b1v) + (b2v + b3)) * dinv[r]);
        }
    }
}

// agg layer1: coalesced gather (16 lanes per src row, bf16 L2-resident) + fused gemm2
__global__ __launch_bounds__(256) void k_agg1g2(const unsigned* __restrict__ ebuf2,
                                                const int* __restrict__ bstart,
                                                const __hip_bfloat16* __restrict__ hs1b,
                                                const float* __restrict__ b1,
                                                const float* __restrict__ W2,
                                                const float* __restrict__ dinv,
                                                float* __restrict__ hs2p, int N) {
    __shared__ float acc[BN][F_HID + 1];
    __shared__ float w2[F_HID * F_OUT];
    __shared__ float b1s[F_HID];
    int b = blockIdx.x, t = threadIdx.x;
    for (int i = t; i < BN * (F_HID + 1); i += 256) ((float*)acc)[i] = 0.f;
    if (t < F_HID * F_OUT) w2[t] = W2[t];
    if (t < F_HID) b1s[t] = b1[t];
    __syncthreads();
    int s0 = bstart[b], s1 = bstart[b + 1];
    int w = t >> 6;            // wave 0..3
    int slot = (t >> 4) & 3;   // 4 edges per wave-group
    int j = t & 15;            // feature
    // unroll 2: each wave-iter covers 8 edges; block-iter = 32 edges
    for (int base = s0 + w * 8; base < s1; base += 32) {
        int iA = base + slot;
        int iB = base + 4 + slot;
        unsigned rA = (iA < s1) ? ebuf2[iA] : SENT;
        unsigned rB = (iB < s1) ? ebuf2[iB] : SENT;
        float vA = 0.f, vB = 0.f;
        if (rA != SENT) vA = __bfloat162float(hs1b[(size_t)(rA >> 6) * F_HID + j]);
        if (rB != SENT) vB = __bfloat162float(hs1b[(size_t)(rB >> 6) * F_HID + j]);
        if (rA != SENT) atomicAdd(&acc[rA & 63][j], vA);
        if (rB != SENT) atomicAdd(&acc[rB & 63][j], vB);
    }
    __syncthreads();
    if (t < BN) {
        int node = b * BN + t;
        if (node < N) {
            float di = dinv[node];
            const __hip_bfloat16* hr = hs1b + (size_t)node * F_HID;
            float o0 = 0.f, o1 = 0.f, o2 = 0.f;
#pragma unroll
            for (int jj = 0; jj < F_HID; ++jj) {
                float v = fmaxf(b1s[jj] + di * (__bfloat162float(hr[jj]) + acc[t][jj]), 0.f);
                o0 = fmaf(v, w2[jj * 3 + 0], o0);
                o1 = fmaf(v, w2[jj * 3 + 1], o1);
                o2 = fmaf(v, w2[jj * 3 + 2], o2);
            }
            hs2p[(size_t)node * 4 + 0] = o0 * di;
            hs2p[(size_t)node * 4 + 1] = o1 * di;
            hs2p[(size_t)node * 4 + 2] = o2 * di;
            hs2p[(size_t)node * 4 + 3] = 0.f;   // pad read by c==3 lanes in agg2
        }
    }
}

// agg layer2: coalesced gather (4 lanes per src row, padded f32) + fused log_softmax
__global__ __launch_bounds__(256) void k_agg2lsm(const unsigned* __restrict__ ebuf2,
                                                 const int* __restrict__ bstart,
                                                 const float* __restrict__ hs2p,
                                                 const float* __restrict__ b2,
                                                 const float* __restrict__ dinv,
                                                 float* __restrict__ out, int N) {
    __shared__ float acc[BN][4];
    int b = blockIdx.x, t = threadIdx.x;
    for (int i = t; i < BN * 4; i += 256) ((float*)acc)[i] = 0.f;
    __syncthreads();
    int s0 = bstart[b], s1 = bstart[b + 1];
    int w = t >> 6;
    int slot = (t >> 2) & 15;  // 16 edges per wave-group
    int c = t & 3;
    for (int base = s0 + w * 32; base < s1; base += 128) {
        int iA = base + slot;
        int iB = base + 16 + slot;
        unsigned rA = (iA < s1) ? ebuf2[iA] : SENT;
        unsigned rB = (iB < s1) ? ebuf2[iB] : SENT;
        float vA = 0.f, vB = 0.f;
        if (rA != SENT) vA = hs2p[(size_t)(rA >> 6) * 4 + c];
        if (rB != SENT) vB = hs2p[(size_t)(rB >> 6) * 4 + c];
        if (rA != SENT && c < 3) atomicAdd(&acc[rA & 63][c], vA);
        if (rB != SENT && c < 3) atomicAdd(&acc[rB & 63][c], vB);
    }
    __syncthreads();
    if (t < BN) {
        int node = b * BN + t;
        if (node < N) {
            float di = dinv[node];
            const float* hr = hs2p + (size_t)node * 4;
            float a0 = b2[0] + di * (hr[0] + acc[t][0]);
            float a1 = b2[1] + di * (hr[1] + acc[t][1]);
            float a2 = b2[2] + di * (hr[2] + acc[t][2]);
            float m = fmaxf(a0, fmaxf(a1, a2));
            float l = logf(expf(a0 - m) + expf(a1 - m) + expf(a2 - m));
            out[(size_t)node * 3 + 0] = a0 - m - l;
            out[(size_t)node * 3 + 1] = a1 - m - l;
            out[(size_t)node * 3 + 2] = a2 - m - l;
        }
    }
}

extern "C" void kernel_launch(void* const* d_in, const int* in_sizes, int n_in,
                              void* d_out, int out_size, void* d_ws, size_t ws_size,
                              hipStream_t stream) {
    const float* x = (const float*)d_in[0];
    const int* ei = (const int*)d_in[1];
    const float* W1 = (const float*)d_in[2];
    const float* b1 = (const float*)d_in[3];
    const float* W2 = (const float*)d_in[4];
    const float* b2 = (const float*)d_in[5];
    float* out = (float*)d_out;

    const int N = in_sizes[0] / F_IN;        // 100000
    const int E = in_sizes[1] / 2;           // 3200000
    const int NBUCK = (N + BN - 1) / BN;     // 1563 (<=MAXB)
    const int NCH = (E + CE - 1) / CE;       // 391  (<=512 for k_scanchunks)

    char* p = (char*)d_ws;
    auto alloc = [&](size_t bytes) {
        char* r = p;
        p += (bytes + 255) & ~(size_t)255;
        return r;
    };
    int*            degi   = (int*)alloc((size_t)N * 4);
    float*          dinv   = (float*)alloc((size_t)N * 4);
    int*            hist   = (int*)alloc((size_t)NCH * NBUCK * 4);   // ~2.4 MB
    int*            tot    = (int*)alloc((size_t)NBUCK * 4);
    int*            bstart = (int*)alloc(((size_t)NBUCK + 1) * 4);
    unsigned*       ebuf2  = (unsigned*)alloc((size_t)E * 4);        // 12.8 MB
    __hip_bfloat16* hs1b   = (__hip_bfloat16*)alloc((size_t)N * F_HID * 2);  // 3.2 MB (L2-fits)
    float*          hs2p   = (float*)alloc((size_t)N * 4 * 4);       // 1.6 MB padded

    hipMemsetAsync(degi, 0, (size_t)N * 4, stream);

    k_passA<<<NCH, 1024, 0, stream>>>(ei, E, N, NBUCK, hist, degi);
    k_dinv<<<(N + 255) / 256, 256, 0, stream>>>(degi, dinv, N);
    k_scanchunks<<<NBUCK, 512, 0, stream>>>(hist, NCH, NBUCK, tot);
    k_scanbuckets<<<1, 512, 0, stream>>>(tot, NBUCK, E, bstart);
    k_passB<<<NCH, 1024, 0, stream>>>(ei, E, N, NBUCK, hist, bstart, ebuf2);
    k_gemm1<<<(N + 63) / 64, 256, 0, stream>>>(x, W1, dinv, hs1b, N);
    k_agg1g2<<<NBUCK, 256, 0, stream>>>(ebuf2, bstart, hs1b, b1, W2, dinv, hs2p, N);
    k_agg2lsm<<<NBUCK, 256, 0, stream>>>(ebuf2, bstart, hs2p, b2, dinv, out, N);
}

// Round 7
// 359.615 us; speedup vs baseline: 1.8976x; 1.8424x over previous
//
#include <hip/hip_runtime.h>
#include <hip/hip_bf16.h>

#define F_IN 500
#define F_HID 16
#define F_OUT 3
#define BN 64            // dst-nodes per bucket
#define CE 8192          // edges per chunk (partition build)
#define TILE 2048        // edges per sort-tile in agg kernels
#define MAXB 2048        // static LDS bound, >= NBUCK=1563
#define WPAD 501         // padded W1 row stride in LDS

__device__ __forceinline__ int clampi(int v, int lo, int hi) {
    return min(max(v, lo), hi);
}

__device__ __forceinline__ float bf2f(unsigned short u) {
    return __uint_as_float((unsigned)u << 16);
}

// A: per-chunk bucket histogram (LDS) + fused per-node degree count
__global__ __launch_bounds__(1024) void k_passA(const int* __restrict__ ei, int E, int N,
                                                int NBUCK, int* __restrict__ hist,
                                                int* __restrict__ degi) {
    __shared__ int lh[MAXB];
    int c = blockIdx.x;
    for (int i = threadIdx.x; i < NBUCK; i += 1024) lh[i] = 0;
    __syncthreads();
    int base = c * CE, lim = min(base + CE, E);
    for (int e = base + (int)threadIdx.x; e < lim; e += 1024) {
        int d = clampi(ei[(size_t)E + e], 0, N - 1);
        atomicAdd(&lh[d >> 6], 1);
        atomicAdd(&degi[d], 1);
    }
    __syncthreads();
    for (int i = threadIdx.x; i < NBUCK; i += 1024) hist[(size_t)c * NBUCK + i] = lh[i];
}

// S1: exclusive scan down each bucket column (over NCH<=512 chunks); tot[b]=column total
__global__ __launch_bounds__(512) void k_scanchunks(int* __restrict__ hist, int NCH,
                                                    int NBUCK, int* __restrict__ tot) {
    __shared__ int s[512];
    int b = blockIdx.x, t = threadIdx.x;
    int v = (t < NCH) ? hist[(size_t)t * NBUCK + b] : 0;
    s[t] = v;
    __syncthreads();
    for (int off = 1; off < 512; off <<= 1) {
        int add = (t >= off) ? s[t - off] : 0;
        __syncthreads();
        s[t] += add;
        __syncthreads();
    }
    if (t < NCH) hist[(size_t)t * NBUCK + b] = s[t] - v;
    if (t == 511) tot[b] = s[511];
}

// S2: exclusive scan over NBUCK bucket totals (NBUCK>512: strided per-thread ranges)
__global__ __launch_bounds__(512) void k_scanbuckets(const int* __restrict__ tot, int NBUCK,
                                                     int E, int* __restrict__ bstart) {
    __shared__ int s[512];
    int t = threadIdx.x;
    int per = (NBUCK + 511) / 512;
    int lo = t * per, hi = min(lo + per, NBUCK);
    int sum = 0;
    for (int i = lo; i < hi; ++i) sum += tot[i];
    s[t] = sum;
    __syncthreads();
    for (int off = 1; off < 512; off <<= 1) {
        int add = (t >= off) ? s[t - off] : 0;
        __syncthreads();
        s[t] += add;
        __syncthreads();
    }
    int run = s[t] - sum;
    for (int i = lo; i < hi; ++i) {
        bstart[i] = run;
        run += tot[i];
    }
    if (t == 0) bstart[NBUCK] = E;
}

// dinv = rsqrt(deg + 1)
__global__ void k_dinv(const int* __restrict__ degi, float* __restrict__ dinv, int N) {
    int i = blockIdx.x * blockDim.x + threadIdx.x;
    if (i >= N) return;
    dinv[i] = rsqrtf((float)degi[i] + 1.0f);
}

// B: scatter records (src<<6 | dst&63) into bucket-grouped ebuf2
__global__ __launch_bounds__(1024) void k_passB(const int* __restrict__ ei, int E, int N,
                                                int NBUCK, const int* __restrict__ hist,
                                                const int* __restrict__ bstart,
                                                unsigned* __restrict__ ebuf2) {
    __shared__ int loff[MAXB];
    __shared__ int lcnt[MAXB];
    int c = blockIdx.x;
    for (int i = threadIdx.x; i < NBUCK; i += 1024) {
        loff[i] = bstart[i] + hist[(size_t)c * NBUCK + i];
        lcnt[i] = 0;
    }
    __syncthreads();
    int base = c * CE, lim = min(base + CE, E);
    for (int e = base + (int)threadIdx.x; e < lim; e += 1024) {
        int s = clampi(ei[e], 0, N - 1);
        int d = clampi(ei[(size_t)E + e], 0, N - 1);
        int b = d >> 6;
        int pos = loff[b] + atomicAdd(&lcnt[b], 1);
        ebuf2[pos] = ((unsigned)s << 6) | (unsigned)(d & 63);
    }
}

// hs1b = bf16( (x @ W1) * dinv[row] ); thread = 4 rows x 1 col
__global__ __launch_bounds__(256) void k_gemm1(const float* __restrict__ x,
                                               const float* __restrict__ W1,
                                               const float* __restrict__ dinv,
                                               __hip_bfloat16* __restrict__ hs1b, int N) {
    __shared__ float w[F_HID * WPAD];
    for (int idx = threadIdx.x; idx < F_IN * F_HID; idx += 256) {
        int k = idx >> 4, j = idx & 15;
        w[j * WPAD + k] = W1[idx];
    }
    __syncthreads();
    int wave = threadIdx.x >> 6, lane = threadIdx.x & 63;
    int slot = lane >> 4, j = lane & 15;
    int r0 = blockIdx.x * 64 + wave * 16 + slot * 4;
    const float* wr = w + j * WPAD;
    if (r0 + 4 <= N) {
        const float* x0 = x + (size_t)r0 * F_IN;
        float a0 = 0.f, a1 = 0.f, a2 = 0.f, a3 = 0.f;
#pragma unroll 5
        for (int k = 0; k < F_IN; k += 4) {
            float4 wv = *(const float4*)(wr + k);
            float4 v0 = *(const float4*)(x0 + k);
            float4 v1 = *(const float4*)(x0 + F_IN + k);
            float4 v2 = *(const float4*)(x0 + 2 * F_IN + k);
            float4 v3 = *(const float4*)(x0 + 3 * F_IN + k);
            a0 = fmaf(v0.x, wv.x, fmaf(v0.y, wv.y, fmaf(v0.z, wv.z, fmaf(v0.w, wv.w, a0))));
            a1 = fmaf(v1.x, wv.x, fmaf(v1.y, wv.y, fmaf(v1.z, wv.z, fmaf(v1.w, wv.w, a1))));
            a2 = fmaf(v2.x, wv.x, fmaf(v2.y, wv.y, fmaf(v2.z, wv.z, fmaf(v2.w, wv.w, a2))));
            a3 = fmaf(v3.x, wv.x, fmaf(v3.y, wv.y, fmaf(v3.z, wv.z, fmaf(v3.w, wv.w, a3))));
        }
        hs1b[(size_t)(r0 + 0) * F_HID + j] = __float2bfloat16(a0 * dinv[r0 + 0]);
        hs1b[(size_t)(r0 + 1) * F_HID + j] = __float2bfloat16(a1 * dinv[r0 + 1]);
        hs1b[(size_t)(r0 + 2) * F_HID + j] = __float2bfloat16(a2 * dinv[r0 + 2]);
        hs1b[(size_t)(r0 + 3) * F_HID + j] = __float2bfloat16(a3 * dinv[r0 + 3]);
    } else {
        for (int rr = 0; rr < 4; ++rr) {
            int r = r0 + rr;
            if (r >= N) break;
            float b0 = 0.f, b1v = 0.f, b2v = 0.f, b3 = 0.f;
            const float* xr = x + (size_t)r * F_IN;
            for (int k = 0; k < F_IN; k += 4) {
                float4 xv = *(const float4*)(xr + k);
                float4 wv = *(const float4*)(wr + k);
                b0 = fmaf(xv.x, wv.x, b0);
                b1v = fmaf(xv.y, wv.y, b1v);
                b2v = fmaf(xv.z, wv.z, b2v);
                b3 = fmaf(xv.w, wv.w, b3);
            }
            hs1b[(size_t)r * F_HID + j] = __float2bfloat16(((b0 + b1v) + (b2v + b3)) * dinv[r]);
        }
    }
}

// agg layer1: tile counting-sort in LDS (int atomics only) + register accumulation
// thread = (node nl = t>>2, feature-quarter q = t&3). Fused gemm2 epilogue.
__global__ __launch_bounds__(256) void k_agg1g2(const unsigned* __restrict__ ebuf2,
                                                const int* __restrict__ bstart,
                                                const __hip_bfloat16* __restrict__ hs1b,
                                                const float* __restrict__ b1,
                                                const float* __restrict__ W2,
                                                const float* __restrict__ dinv,
                                                float* __restrict__ hs2p, int N) {
    __shared__ unsigned rec[TILE];   // 8 KB
    __shared__ unsigned srt[TILE];   // 8 KB, src indices sorted by dst-local
    __shared__ int cnt[BN], offs[BN], ocur[BN];
    __shared__ float w2s[F_HID * F_OUT];
    __shared__ float b1s[F_HID];
    int b = blockIdx.x, t = threadIdx.x;
    if (t < F_HID * F_OUT) w2s[t] = W2[t];
    if (t < F_HID) b1s[t] = b1[t];
    int s0 = bstart[b], s1 = bstart[b + 1];
    int nl = t >> 2, q = t & 3;
    float ac0 = 0.f, ac1 = 0.f, ac2 = 0.f, ac3 = 0.f;

    for (int tb = s0; tb < s1; tb += TILE) {
        int nv = min(TILE, s1 - tb);
        if (t < BN) cnt[t] = 0;
        for (int i = t; i < nv; i += 256) rec[i] = ebuf2[tb + i];
        __syncthreads();
        for (int i = t; i < nv; i += 256) atomicAdd(&cnt[rec[i] & 63], 1);
        __syncthreads();
        if (t < 64) {  // wave 0: Kogge-Stone inclusive scan of 64 bins
            int v = cnt[t];
            int xp = v;
#pragma unroll
            for (int d = 1; d < 64; d <<= 1) {
                int y = __shfl_up(xp, d);
                if (t >= d) xp += y;
            }
            offs[t] = xp - v;
            ocur[t] = xp - v;
        }
        __syncthreads();
        for (int i = t; i < nv; i += 256) {
            unsigned r = rec[i];
            int pos = atomicAdd(&ocur[r & 63], 1);
            srt[pos] = r >> 6;
        }
        __syncthreads();
        // register accumulation over this node's segment (4 lanes = 4 quarters, 32B/edge)
        int gs = offs[nl], ge = gs + cnt[nl];
        int i = gs;
        for (; i + 1 < ge; i += 2) {
            unsigned sA = srt[i], sB = srt[i + 1];
            ushort4 uA = *(const ushort4*)(hs1b + (size_t)sA * F_HID + q * 4);
            ushort4 uB = *(const ushort4*)(hs1b + (size_t)sB * F_HID + q * 4);
            ac0 += bf2f(uA.x) + bf2f(uB.x);
            ac1 += bf2f(uA.y) + bf2f(uB.y);
            ac2 += bf2f(uA.z) + bf2f(uB.z);
            ac3 += bf2f(uA.w) + bf2f(uB.w);
        }
        if (i < ge) {
            unsigned sA = srt[i];
            ushort4 uA = *(const ushort4*)(hs1b + (size_t)sA * F_HID + q * 4);
            ac0 += bf2f(uA.x);
            ac1 += bf2f(uA.y);
            ac2 += bf2f(uA.z);
            ac3 += bf2f(uA.w);
        }
        __syncthreads();  // protect rec/srt/cnt reuse
    }

    int node = b * BN + nl;
    if (node < N) {
        float di = dinv[node];
        const __hip_bfloat16* hp = hs1b + (size_t)node * F_HID + q * 4;
        ushort4 us = *(const ushort4*)hp;
        float v0 = fmaxf(b1s[q * 4 + 0] + di * (bf2f(us.x) + ac0), 0.f);
        float v1 = fmaxf(b1s[q * 4 + 1] + di * (bf2f(us.y) + ac1), 0.f);
        float v2 = fmaxf(b1s[q * 4 + 2] + di * (bf2f(us.z) + ac2), 0.f);
        float v3 = fmaxf(b1s[q * 4 + 3] + di * (bf2f(us.w) + ac3), 0.f);
        float o0 = v0 * w2s[(q * 4 + 0) * 3 + 0] + v1 * w2s[(q * 4 + 1) * 3 + 0] +
                   v2 * w2s[(q * 4 + 2) * 3 + 0] + v3 * w2s[(q * 4 + 3) * 3 + 0];
        float o1 = v0 * w2s[(q * 4 + 0) * 3 + 1] + v1 * w2s[(q * 4 + 1) * 3 + 1] +
                   v2 * w2s[(q * 4 + 2) * 3 + 1] + v3 * w2s[(q * 4 + 3) * 3 + 1];
        float o2 = v0 * w2s[(q * 4 + 0) * 3 + 2] + v1 * w2s[(q * 4 + 1) * 3 + 2] +
                   v2 * w2s[(q * 4 + 2) * 3 + 2] + v3 * w2s[(q * 4 + 3) * 3 + 2];
        o0 += __shfl_xor(o0, 1); o0 += __shfl_xor(o0, 2);
        o1 += __shfl_xor(o1, 1); o1 += __shfl_xor(o1, 2);
        o2 += __shfl_xor(o2, 1); o2 += __shfl_xor(o2, 2);
        if (q == 0) {
            float4 r = make_float4(o0 * di, o1 * di, o2 * di, 0.f);
            *(float4*)(hs2p + (size_t)node * 4) = r;
        }
    }
}

// agg layer2: same tile-sort, register accumulation (node nl, class c) + log_softmax
__global__ __launch_bounds__(256) void k_agg2lsm(const unsigned* __restrict__ ebuf2,
                                                 const int* __restrict__ bstart,
                                                 const float* __restrict__ hs2p,
                                                 const float* __restrict__ b2,
                                                 const float* __restrict__ dinv,
                                                 float* __restrict__ out, int N) {
    __shared__ unsigned rec[TILE];
    __shared__ unsigned srt[TILE];
    __shared__ int cnt[BN], offs[BN], ocur[BN];
    int b = blockIdx.x, t = threadIdx.x;
    int s0 = bstart[b], s1 = bstart[b + 1];
    int nl = t >> 2, c = t & 3;
    float acc = 0.f;

    for (int tb = s0; tb < s1; tb += TILE) {
        int nv = min(TILE, s1 - tb);
        if (t < BN) cnt[t] = 0;
        for (int i = t; i < nv; i += 256) rec[i] = ebuf2[tb + i];
        __syncthreads();
        for (int i = t; i < nv; i += 256) atomicAdd(&cnt[rec[i] & 63], 1);
        __syncthreads();
        if (t < 64) {
            int v = cnt[t];
            int xp = v;
#pragma unroll
            for (int d = 1; d < 64; d <<= 1) {
                int y = __shfl_up(xp, d);
                if (t >= d) xp += y;
            }
            offs[t] = xp - v;
            ocur[t] = xp - v;
        }
        __syncthreads();
        for (int i = t; i < nv; i += 256) {
            unsigned r = rec[i];
            int pos = atomicAdd(&ocur[r & 63], 1);
            srt[pos] = r >> 6;
        }
        __syncthreads();
        int gs = offs[nl], ge = gs + cnt[nl];
        int i = gs;
        for (; i + 1 < ge; i += 2) {
            unsigned sA = srt[i], sB = srt[i + 1];
            float vA = hs2p[(size_t)sA * 4 + c];
            float vB = hs2p[(size_t)sB * 4 + c];
            acc += vA + vB;
        }
        if (i < ge) acc += hs2p[(size_t)srt[i] * 4 + c];
        __syncthreads();
    }

    int node = b * BN + nl;
    if (node < N) {
        float di = dinv[node];
        float self = hs2p[(size_t)node * 4 + c];
        float bc = (c < 3) ? b2[c] : 0.f;
        float a = bc + di * (self + acc);   // c==3: garbage, unused
        int wbase = (t & 63) & ~3;
        float a0 = __shfl(a, wbase + 0);
        float a1 = __shfl(a, wbase + 1);
        float a2 = __shfl(a, wbase + 2);
        if (c < 3) {
            float m = fmaxf(a0, fmaxf(a1, a2));
            float l = logf(expf(a0 - m) + expf(a1 - m) + expf(a2 - m));
            out[(size_t)node * 3 + c] = a - m - l;
        }
    }
}

extern "C" void kernel_launch(void* const* d_in, const int* in_sizes, int n_in,
                              void* d_out, int out_size, void* d_ws, size_t ws_size,
                              hipStream_t stream) {
    const float* x = (const float*)d_in[0];
    const int* ei = (const int*)d_in[1];
    const float* W1 = (const float*)d_in[2];
    const float* b1 = (const float*)d_in[3];
    const float* W2 = (const float*)d_in[4];
    const float* b2 = (const float*)d_in[5];
    float* out = (float*)d_out;

    const int N = in_sizes[0] / F_IN;        // 100000
    const int E = in_sizes[1] / 2;           // 3200000
    const int NBUCK = (N + BN - 1) / BN;     // 1563 (<=MAXB)
    const int NCH = (E + CE - 1) / CE;       // 391  (<=512 for k_scanchunks)

    char* p = (char*)d_ws;
    auto alloc = [&](size_t bytes) {
        char* r = p;
        p += (bytes + 255) & ~(size_t)255;
        return r;
    };
    int*            degi   = (int*)alloc((size_t)N * 4);
    float*          dinv   = (float*)alloc((size_t)N * 4);
    int*            hist   = (int*)alloc((size_t)NCH * NBUCK * 4);
    int*            tot    = (int*)alloc((size_t)NBUCK * 4);
    int*            bstart = (int*)alloc(((size_t)NBUCK + 1) * 4);
    unsigned*       ebuf2  = (unsigned*)alloc((size_t)E * 4);
    __hip_bfloat16* hs1b   = (__hip_bfloat16*)alloc((size_t)N * F_HID * 2);
    float*          hs2p   = (float*)alloc((size_t)N * 4 * 4);

    hipMemsetAsync(degi, 0, (size_t)N * 4, stream);

    k_passA<<<NCH, 1024, 0, stream>>>(ei, E, N, NBUCK, hist, degi);
    k_dinv<<<(N + 255) / 256, 256, 0, stream>>>(degi, dinv, N);
    k_scanchunks<<<NBUCK, 512, 0, stream>>>(hist, NCH, NBUCK, tot);
    k_scanbuckets<<<1, 512, 0, stream>>>(tot, NBUCK, E, bstart);
    k_passB<<<NCH, 1024, 0, stream>>>(ei, E, N, NBUCK, hist, bstart, ebuf2);
    k_gemm1<<<(N + 63) / 64, 256, 0, stream>>>(x, W1, dinv, hs1b, N);
    k_agg1g2<<<NBUCK, 256, 0, stream>>>(ebuf2, bstart, hs1b, b1, W2, dinv, hs2p, N);
    k_agg2lsm<<<NBUCK, 256, 0, stream>>>(ebuf2, bstart, hs2p, b2, dinv, out, N);
}